// Round 13
// baseline (142.603 us; speedup 1.0000x reference)
//
#include <hip/hip_runtime.h>

// SignalingModel: X_{t+1} = mml(W @ X_t + X_bias), 60 steps, W 0.24% sparse.
// R10 = R9 structure, SPB=1: grid 512 x 1024 -> 2 blocks/CU (32 waves, 100%
// occupancy) and scalar-f32 state -> random ds_read_b32 gathers are ~2-way
// bank-aliased = FREE (vs b64's 4-way = 1.58x). Per-sample DS bytes and VALU
// unchanged; pure occupancy + conflict win.
// Lessons: LDS atomics 16-25cy (R1/R3); per-step global structure re-reads =
// 20x expansion (R4); step-invariant entry reads belong in registers, which
// requires fixed trip counts + compile-time indexing (R9, VGPR 28->52);
// barrier makes block time = slowest wave -> zigzag degree pairing (R7/R8);
// grid=1 block/CU caps occupancy at 50% (R9).

#define NN 2048
#define STEPS 60
#define LEAKV 0.01f
#define EMAX 10240
#define TPB 1024
#define NB 64
#define EPT 12            // register slots per thread (zigzag pair-sum p99 ~13)

__device__ __forceinline__ float mml_f(float x) {
  if (x < 0.0f)      return LEAKV * x;
  else if (x < 0.5f) return x;
  else               return 1.0f - 0.25f / x;
}

// --- build pipeline (unchanged from R8/R9) --------------------------------

__global__ __launch_bounds__(64) void count_row(const float* __restrict__ W,
                                                int* __restrict__ cnt) {
  const int n = blockIdx.x, lane = threadIdx.x;
  int c = 0;
  for (int c0 = 0; c0 < NN; c0 += 64) {
    float w = W[n * NN + c0 + lane];
    c += __popcll(__ballot(w != 0.0f));
  }
  if (lane == 0) cnt[n] = c;
}

__global__ __launch_bounds__(1024) void scan2048(const int* __restrict__ cnt,
                                                 int* __restrict__ base) {
  __shared__ int sb[2][NN];
  const int t = threadIdx.x;
  sb[0][t] = cnt[t];
  sb[0][t + 1024] = cnt[t + 1024];
  __syncthreads();
  int p = 0;
  for (int off = 1; off < NN; off <<= 1) {
    int i0 = t, i1 = t + 1024;
    sb[p ^ 1][i0] = sb[p][i0] + (i0 >= off ? sb[p][i0 - off] : 0);
    sb[p ^ 1][i1] = sb[p][i1] + (i1 >= off ? sb[p][i1 - off] : 0);
    __syncthreads();
    p ^= 1;
  }
  base[t] = sb[p][t] - cnt[t];
  base[t + 1024] = sb[p][t + 1024] - cnt[t + 1024];
  if (t == 1023) base[NN] = sb[p][NN - 1];
}

__global__ __launch_bounds__(64) void fill_edges(const float* __restrict__ W,
                                                 const int* __restrict__ base,
                                                 uint2* __restrict__ pg) {
  const int n = blockIdx.x, lane = threadIdx.x;
  const int b = base[n];
  int off = 0;
  for (int c0 = 0; c0 < NN; c0 += 64) {
    float w = W[n * NN + c0 + lane];
    unsigned long long m = __ballot(w != 0.0f);
    if (w != 0.0f) {
      int e = b + off + __popcll(m & ((1ull << lane) - 1ull));
      pg[e] = make_uint2(__float_as_uint(w), (unsigned)(c0 + lane));
    }
    off += __popcll(m);
  }
}

// degree counting-sort: perm[rank]=node, ascending. Unstable within bucket --
// output-invariant (per-node edge order preserved regardless of owner thread).
__global__ __launch_bounds__(1024) void sortnodes(const int* __restrict__ cnt,
                                                  int* __restrict__ perm) {
  __shared__ int bases[NB];
  const int t = threadIdx.x;
  if (t < NB) bases[t] = 0;
  __syncthreads();
  int d0 = min(cnt[t], NB - 1);
  int d1 = min(cnt[t + 1024], NB - 1);
  atomicAdd(&bases[d0], 1);
  atomicAdd(&bases[d1], 1);
  __syncthreads();
  if (t == 0) {
    int acc = 0;
    for (int i = 0; i < NB; ++i) { int h = bases[i]; bases[i] = acc; acc += h; }
  }
  __syncthreads();
  perm[atomicAdd(&bases[d0], 1)] = t;
  perm[atomicAdd(&bases[d1], 1)] = t + 1024;
}

// zigzag pair + thread-contiguous edge re-layout (CSR order preserved).
__global__ __launch_bounds__(1024) void pair_layout(const int* __restrict__ cnt,
                                                    const int* __restrict__ base,
                                                    const uint2* __restrict__ pg,
                                                    const int* __restrict__ perm,
                                                    uint2* __restrict__ e2,
                                                    int* __restrict__ tb,
                                                    int* __restrict__ tmid,
                                                    int* __restrict__ pa,
                                                    int* __restrict__ pb) {
  __shared__ int sc[2][1024];
  const int t = threadIdx.x;
  const int nA = perm[t], nB = perm[2047 - t];
  const int dA = cnt[nA], dB = cnt[nB];
  sc[0][t] = dA + dB;
  __syncthreads();
  int p = 0;
  for (int off = 1; off < 1024; off <<= 1) {
    sc[p ^ 1][t] = sc[p][t] + (t >= off ? sc[p][t - off] : 0);
    __syncthreads();
    p ^= 1;
  }
  const int b = sc[p][t] - (dA + dB);
  tb[t] = b;
  tmid[t] = b + dA;
  pa[t] = nA;
  pb[t] = nB;
  if (t == 1023) tb[1024] = sc[p][t];
  const int bA = base[nA], bB = base[nB];
  for (int k = 0; k < dA; ++k) e2[b + k] = pg[bA + k];
  for (int k = 0; k < dB; ++k) e2[b + dA + k] = pg[bB + k];
}

// --- simulation -----------------------------------------------------------
// one block = ONE sample; scalar state ping-pong (16 KB); 12 edges/thread in
// registers; 2 blocks/CU. Random b32 gathers ~2-way bank-aliased (free).
__global__ __launch_bounds__(TPB, 8) void sim(const float* __restrict__ Xfull,
                                              const float* __restrict__ bias,
                                              const uint2* __restrict__ e2,
                                              const int* __restrict__ tb,
                                              const int* __restrict__ tmid,
                                              const int* __restrict__ pa,
                                              const int* __restrict__ pb,
                                              float* __restrict__ out) {
  __shared__ float X[2][NN];                      // 16 KB
  const int t = (int)threadIdx.x;
  const int s = (int)blockIdx.x;

  const int nA = pa[t], nB = pb[t];
  const int eA0 = tb[t], eA1 = tmid[t], eB1 = tb[t + 1];

  // hoist edges into registers: static unroll, compile-time indices only.
  float wA[EPT], wB[EPT];
  int boff[EPT];                                  // byte offset into X row
#pragma unroll
  for (int k = 0; k < EPT; ++k) {
    const int idx = eA0 + k;
    const bool val = idx < eB1;
    const uint2 en = e2[val ? idx : eA0];         // clamped, masked below
    const float wv = val ? __uint_as_float(en.x) : 0.0f;
    const bool isA = idx < eA1;
    wA[k] = isA ? wv : 0.0f;
    wB[k] = isA ? 0.0f : wv;
    boff[k] = val ? (int)(en.y * 4u) : 0;
  }

  const float xbA = Xfull[(size_t)s * NN + nA] + bias[nA];
  const float xbB = Xfull[(size_t)s * NN + nB] + bias[nB];
  // X1 = mml(W@0 + xb) = mml(xb)
  X[0][nA] = mml_f(xbA);
  X[0][nB] = mml_f(xbB);
  __syncthreads();

  int cur = 0;
  float yA = 0.f, yB = 0.f;
  for (int it = 0; it < STEPS - 1; ++it) {        // produces X2..X60
    const char* __restrict__ Xc = (const char*)&X[cur][0];
    float aA = xbA, aB = xbB;
#pragma unroll
    for (int k = 0; k < EPT; ++k) {               // zero divergence
      const float v = *(const float*)(Xc + boff[k]);
      aA += wA[k] * v;
      aB += wB[k] * v;
    }
    for (int e = eA0 + EPT; e < eB1; ++e) {       // rare spill lanes
      const uint2 en = e2[e];                     // L1-hot global
      const float w = __uint_as_float(en.x);
      const float v = *(const float*)(Xc + en.y * 4u);
      if (e < eA1) aA += w * v; else aB += w * v;
    }
    yA = mml_f(aA); yB = mml_f(aB);
    X[cur ^ 1][nA] = yA;
    X[cur ^ 1][nB] = yB;
    __syncthreads();                              // one barrier per step
    cur ^= 1;
  }

  out[(size_t)s * NN + nA] = yA;
  out[(size_t)s * NN + nB] = yB;
}

extern "C" void kernel_launch(void* const* d_in, const int* in_sizes, int n_in,
                              void* d_out, int out_size, void* d_ws, size_t ws_size,
                              hipStream_t stream) {
  const float* Xfull = (const float*)d_in[0];   // (B, N) f32
  const float* W     = (const float*)d_in[1];   // (N, N) f32
  const float* bias  = (const float*)d_in[2];   // (N, 1) f32
  float* out = (float*)d_out;

  // ws: pg[EMAX]u2 | e2[EMAX]u2 | cnt[NN] | base[NN+1] | perm[NN] | tb[1025] | tmid[1024] | pa[1024] | pb[1024]
  char* ws = (char*)d_ws;
  uint2* pg = (uint2*)ws;                               ws += (size_t)EMAX * 8;
  uint2* e2 = (uint2*)ws;                               ws += (size_t)EMAX * 8;
  int* cnt  = (int*)ws;                                 ws += (size_t)NN * 4;
  int* base = (int*)ws;                                 ws += (size_t)(NN + 1) * 4;
  int* perm = (int*)ws;                                 ws += (size_t)NN * 4;
  int* tb   = (int*)ws;                                 ws += (size_t)1025 * 4;
  int* tmid = (int*)ws;                                 ws += (size_t)1024 * 4;
  int* pa   = (int*)ws;                                 ws += (size_t)1024 * 4;
  int* pb   = (int*)ws;

  const int B = in_sizes[0] / NN;   // 512

  hipMemsetAsync(pg, 0, (size_t)EMAX * 16, stream);   // pg + e2 tails defined
  count_row<<<NN, 64, 0, stream>>>(W, cnt);
  scan2048<<<1, 1024, 0, stream>>>(cnt, base);
  fill_edges<<<NN, 64, 0, stream>>>(W, base, pg);
  sortnodes<<<1, 1024, 0, stream>>>(cnt, perm);
  pair_layout<<<1, 1024, 0, stream>>>(cnt, base, pg, perm, e2, tb, tmid, pa, pb);
  sim<<<B, TPB, 0, stream>>>(Xfull, bias, e2, tb, tmid, pa, pb, out);
}

// Round 14
// 119.009 us; speedup vs baseline: 1.1983x; 1.1983x over previous
//
#include <hip/hip_runtime.h>

// SignalingModel: X_{t+1} = mml(W @ X_t + X_bias), 60 steps, W 0.24% sparse.
// R11 = R9 (SPB=2, b64 gathers, register edges) + three overhead cuts:
//  (1) EPT=14 -> per-step global spill loop almost never executes (it was in
//      nearly every wave's barrier critical path at EPT=12).
//  (2) node RENUMBERING: thread t owns new-ids {2t,2t+1} -> the two scattered
//      ds_write_b64 fuse into ONE conflict-free ds_write_b128. Per-node CSR
//      sum order unchanged -> output bitwise identical.
//  (3) double-step unroll, ping-pong buffer as compile-time 0/16384 folded
//      into ds offset immediates -> zero per-step address arithmetic.
// Lessons: LDS pipe (instr x conflict) is the serial resource; batch samples
// into wide gathers (R10 regression); register edges need fixed trip counts +
// compile-time indexing (R9); zigzag degree pairing for barrier balance (R8).

#define NN 2048
#define STEPS 60
#define LEAKV 0.01f
#define EMAX 10240
#define TPB 1024
#define SPB 2
#define NB 64
#define EPT 14            // register slots per thread (zigzag pair-sum ~p95+)
#define BUF1 16384        // byte offset of second state buffer (NN*8)

__device__ __forceinline__ float mml_f(float x) {
  if (x < 0.0f)      return LEAKV * x;
  else if (x < 0.5f) return x;
  else               return 1.0f - 0.25f / x;
}

// --- build pipeline -------------------------------------------------------

__global__ __launch_bounds__(64) void count_row(const float* __restrict__ W,
                                                int* __restrict__ cnt) {
  const int n = blockIdx.x, lane = threadIdx.x;
  int c = 0;
  for (int c0 = 0; c0 < NN; c0 += 64) {
    float w = W[n * NN + c0 + lane];
    c += __popcll(__ballot(w != 0.0f));
  }
  if (lane == 0) cnt[n] = c;
}

__global__ __launch_bounds__(1024) void scan2048(const int* __restrict__ cnt,
                                                 int* __restrict__ base) {
  __shared__ int sb[2][NN];
  const int t = threadIdx.x;
  sb[0][t] = cnt[t];
  sb[0][t + 1024] = cnt[t + 1024];
  __syncthreads();
  int p = 0;
  for (int off = 1; off < NN; off <<= 1) {
    int i0 = t, i1 = t + 1024;
    sb[p ^ 1][i0] = sb[p][i0] + (i0 >= off ? sb[p][i0 - off] : 0);
    sb[p ^ 1][i1] = sb[p][i1] + (i1 >= off ? sb[p][i1 - off] : 0);
    __syncthreads();
    p ^= 1;
  }
  base[t] = sb[p][t] - cnt[t];
  base[t + 1024] = sb[p][t + 1024] - cnt[t + 1024];
  if (t == 1023) base[NN] = sb[p][NN - 1];
}

__global__ __launch_bounds__(64) void fill_edges(const float* __restrict__ W,
                                                 const int* __restrict__ base,
                                                 uint2* __restrict__ pg) {
  const int n = blockIdx.x, lane = threadIdx.x;
  const int b = base[n];
  int off = 0;
  for (int c0 = 0; c0 < NN; c0 += 64) {
    float w = W[n * NN + c0 + lane];
    unsigned long long m = __ballot(w != 0.0f);
    if (w != 0.0f) {
      int e = b + off + __popcll(m & ((1ull << lane) - 1ull));
      pg[e] = make_uint2(__float_as_uint(w), (unsigned)(c0 + lane));
    }
    off += __popcll(m);
  }
}

// degree counting-sort: perm[rank]=node, ascending. Unstable within bucket --
// output-invariant (per-node CSR edge order preserved wherever it lands).
__global__ __launch_bounds__(1024) void sortnodes(const int* __restrict__ cnt,
                                                  int* __restrict__ perm) {
  __shared__ int bases[NB];
  const int t = threadIdx.x;
  if (t < NB) bases[t] = 0;
  __syncthreads();
  int d0 = min(cnt[t], NB - 1);
  int d1 = min(cnt[t + 1024], NB - 1);
  atomicAdd(&bases[d0], 1);
  atomicAdd(&bases[d1], 1);
  __syncthreads();
  if (t == 0) {
    int acc = 0;
    for (int i = 0; i < NB; ++i) { int h = bases[i]; bases[i] = acc; acc += h; }
  }
  __syncthreads();
  perm[atomicAdd(&bases[d0], 1)] = t;
  perm[atomicAdd(&bases[d1], 1)] = t + 1024;
}

// zigzag pair + thread-contiguous edge re-layout (CSR order preserved).
__global__ __launch_bounds__(1024) void pair_layout(const int* __restrict__ cnt,
                                                    const int* __restrict__ base,
                                                    const uint2* __restrict__ pg,
                                                    const int* __restrict__ perm,
                                                    uint2* __restrict__ e2,
                                                    int* __restrict__ tb,
                                                    int* __restrict__ tmid,
                                                    int* __restrict__ pa,
                                                    int* __restrict__ pb) {
  __shared__ int sc[2][1024];
  const int t = threadIdx.x;
  const int nA = perm[t], nB = perm[2047 - t];
  const int dA = cnt[nA], dB = cnt[nB];
  sc[0][t] = dA + dB;
  __syncthreads();
  int p = 0;
  for (int off = 1; off < 1024; off <<= 1) {
    sc[p ^ 1][t] = sc[p][t] + (t >= off ? sc[p][t - off] : 0);
    __syncthreads();
    p ^= 1;
  }
  const int b = sc[p][t] - (dA + dB);
  tb[t] = b;
  tmid[t] = b + dA;
  pa[t] = nA;
  pb[t] = nB;
  if (t == 1023) tb[1024] = sc[p][t];
  const int bA = base[nA], bB = base[nB];
  for (int k = 0; k < dA; ++k) e2[b + k] = pg[bA + k];
  for (int k = 0; k < dB; ++k) e2[b + dA + k] = pg[bB + k];
}

// node renumbering: thread t's nodes become new-ids {2t, 2t+1}
__global__ __launch_bounds__(1024) void renum(const int* __restrict__ pa,
                                              const int* __restrict__ pb,
                                              int* __restrict__ newid) {
  const int t = threadIdx.x;
  newid[pa[t]] = 2 * t;
  newid[pb[t]] = 2 * t + 1;
}

__global__ __launch_bounds__(256) void remap(uint2* __restrict__ e2,
                                             const int* __restrict__ newid) {
  const int e = blockIdx.x * 256 + threadIdx.x;
  e2[e].y = (unsigned)newid[e2[e].y];   // tail entries (src=0) map to a valid id
}

// --- simulation -----------------------------------------------------------
// one block = 2 samples; state float2{s0,s1}[NN] x2 buffers (32 KB static);
// thread t owns new-ids {2t,2t+1}; 14 edges/thread in registers; paired b128
// store; buffer ping-pong via compile-time ds offset immediates.
__global__ __launch_bounds__(TPB, 4) void sim(const float* __restrict__ Xfull,
                                              const float* __restrict__ bias,
                                              const uint2* __restrict__ e2,
                                              const int* __restrict__ tb,
                                              const int* __restrict__ tmid,
                                              const int* __restrict__ pa,
                                              const int* __restrict__ pb,
                                              float* __restrict__ out) {
  __shared__ float2 X[2][NN];                     // 32 KB
  char* Xb = (char*)&X[0][0];
  const int t  = (int)threadIdx.x;
  const int s0 = (int)blockIdx.x * SPB;

  const int eA0 = tb[t], eA1 = tmid[t], eB1 = tb[t + 1];
  const int spill0 = eA0 + EPT;
  const int oldA = pa[t], oldB = pb[t];

  // hoist edges into registers: static unroll, compile-time indices only.
  float wA[EPT], wB[EPT];
  int boff[EPT];                                  // byte offset into a buffer
#pragma unroll
  for (int k = 0; k < EPT; ++k) {
    const int idx = eA0 + k;
    const bool val = idx < eB1;
    const uint2 en = e2[val ? idx : eA0];         // clamped, masked below
    const float wv = val ? __uint_as_float(en.x) : 0.0f;
    const bool isA = idx < eA1;
    wA[k] = isA ? wv : 0.0f;
    wB[k] = isA ? 0.0f : wv;
    boff[k] = val ? (int)(en.y * 8u) : 0;
  }

  const float2 xbA = make_float2(Xfull[(size_t)s0 * NN + oldA] + bias[oldA],
                                 Xfull[(size_t)(s0 + 1) * NN + oldA] + bias[oldA]);
  const float2 xbB = make_float2(Xfull[(size_t)s0 * NN + oldB] + bias[oldB],
                                 Xfull[(size_t)(s0 + 1) * NN + oldB] + bias[oldB]);
  const int wr = t * 16;                          // this thread's store offset

  // X1 = mml(W@0 + xb) = mml(xb) into buffer 0
  *(float4*)(Xb + wr) = make_float4(mml_f(xbA.x), mml_f(xbA.y),
                                    mml_f(xbB.x), mml_f(xbB.y));
  __syncthreads();

  float2 yA, yB;

#define STEP(SRCOFF, DSTOFF)                                                 \
  {                                                                          \
    float2 aA = xbA, aB = xbB;                                               \
    _Pragma("unroll")                                                        \
    for (int k = 0; k < EPT; ++k) {                                          \
      const float2 v = *(const float2*)(Xb + (SRCOFF) + boff[k]);            \
      aA.x += wA[k] * v.x;  aA.y += wA[k] * v.y;                             \
      aB.x += wB[k] * v.x;  aB.y += wB[k] * v.y;                             \
    }                                                                        \
    for (int e = spill0; e < eB1; ++e) {          /* ~never taken */         \
      const uint2 en = e2[e];                                                \
      const float w = __uint_as_float(en.x);                                 \
      const float2 v = *(const float2*)(Xb + (SRCOFF) + (int)(en.y * 8u));   \
      if (e < eA1) { aA.x += w * v.x; aA.y += w * v.y; }                     \
      else         { aB.x += w * v.x; aB.y += w * v.y; }                     \
    }                                                                        \
    yA = make_float2(mml_f(aA.x), mml_f(aA.y));                              \
    yB = make_float2(mml_f(aB.x), mml_f(aB.y));                              \
    *(float4*)(Xb + (DSTOFF) + wr) = make_float4(yA.x, yA.y, yB.x, yB.y);    \
    __syncthreads();                                                         \
  }

  STEP(0, BUF1);                                  // step 2
  for (int i = 0; i < (STEPS - 2) / 2; ++i) {     // 29 double-steps: 3..60
    STEP(BUF1, 0);
    STEP(0, BUF1);
  }
#undef STEP

  // final values in registers; de-interleave to (B, N) rows (one-time)
  out[(size_t)s0 * NN + oldA]       = yA.x;
  out[(size_t)(s0 + 1) * NN + oldA] = yA.y;
  out[(size_t)s0 * NN + oldB]       = yB.x;
  out[(size_t)(s0 + 1) * NN + oldB] = yB.y;
}

extern "C" void kernel_launch(void* const* d_in, const int* in_sizes, int n_in,
                              void* d_out, int out_size, void* d_ws, size_t ws_size,
                              hipStream_t stream) {
  const float* Xfull = (const float*)d_in[0];   // (B, N) f32
  const float* W     = (const float*)d_in[1];   // (N, N) f32
  const float* bias  = (const float*)d_in[2];   // (N, 1) f32
  float* out = (float*)d_out;

  // ws: pg[EMAX]u2 | e2[EMAX]u2 | cnt[NN] | base[NN+1] | perm[NN] | newid[NN] |
  //     tb[1025] | tmid[1024] | pa[1024] | pb[1024]
  char* ws = (char*)d_ws;
  uint2* pg  = (uint2*)ws;                              ws += (size_t)EMAX * 8;
  uint2* e2  = (uint2*)ws;                              ws += (size_t)EMAX * 8;
  int* cnt   = (int*)ws;                                ws += (size_t)NN * 4;
  int* base  = (int*)ws;                                ws += (size_t)(NN + 1) * 4;
  int* perm  = (int*)ws;                                ws += (size_t)NN * 4;
  int* newid = (int*)ws;                                ws += (size_t)NN * 4;
  int* tb    = (int*)ws;                                ws += (size_t)1025 * 4;
  int* tmid  = (int*)ws;                                ws += (size_t)1024 * 4;
  int* pa    = (int*)ws;                                ws += (size_t)1024 * 4;
  int* pb    = (int*)ws;

  const int B = in_sizes[0] / NN;   // 512

  hipMemsetAsync(pg, 0, (size_t)EMAX * 16, stream);   // pg + e2 tails defined
  count_row<<<NN, 64, 0, stream>>>(W, cnt);
  scan2048<<<1, 1024, 0, stream>>>(cnt, base);
  fill_edges<<<NN, 64, 0, stream>>>(W, base, pg);
  sortnodes<<<1, 1024, 0, stream>>>(cnt, perm);
  pair_layout<<<1, 1024, 0, stream>>>(cnt, base, pg, perm, e2, tb, tmid, pa, pb);
  renum<<<1, 1024, 0, stream>>>(pa, pb, newid);
  remap<<<EMAX / 256, 256, 0, stream>>>(e2, newid);
  sim<<<B / SPB, TPB, 0, stream>>>(Xfull, bias, e2, tb, tmid, pa, pb, out);
}